// Round 12
// baseline (227.152 us; speedup 1.0000x reference)
//
#include <hip/hip_runtime.h>

#define NLAYER 4
#define BATCH  256
#define HID    1024

typedef float f32x4 __attribute__((ext_vector_type(4)));
typedef short short8 __attribute__((ext_vector_type(8)));
typedef unsigned short ushort_t;
typedef unsigned long long u64;

// Raw sync primitives (round-0 proven discipline). All counted VM ops (DMA
// builtin + GLD16 asm) and WAITV/BAR are volatile -> mutual program order.
#define BAR()     asm volatile("s_barrier")
#define WAITV(n)  asm volatile("s_waitcnt vmcnt(" #n ")")
#define DSR(d, a) asm volatile("ds_read_b128 %0, %1" : "=v"(d) : "v"(a))
#define LGKM0_TIE6(a,b,c,d,e,f) \
  asm volatile("s_waitcnt lgkmcnt(0)" \
               : "+v"(a),"+v"(b),"+v"(c),"+v"(d),"+v"(e),"+v"(f))
#define FULLBAR() asm volatile("s_waitcnt vmcnt(0) lgkmcnt(0)\ns_barrier" ::: "memory")
#define GLD16(d, a) asm volatile("global_load_dwordx4 %0, %1, off" : "=v"(d) : "v"(a))
#define WAITV0_TIE8(a,b,c,d,e,f,g,h) \
  asm volatile("s_waitcnt vmcnt(0)" \
               : "+v"(a),"+v"(b),"+v"(c),"+v"(d), \
                 "+v"(e),"+v"(f),"+v"(g),"+v"(h))

__device__ __forceinline__ unsigned short f2bf(float f) {
  unsigned int u = __float_as_uint(f);
  unsigned int r = u + 0x7fffu + ((u >> 16) & 1u);  // RNE
  return (unsigned short)(r >> 16);
}
__device__ __forceinline__ float sigm(float x) { return 1.f / (1.f + __expf(-x)); }
__device__ __forceinline__ float tanh_(float x) { return 2.f / (1.f + __expf(-2.f * x)) - 1.f; }

__device__ __forceinline__ void dma16(const void* g, void* l) {
  __builtin_amdgcn_global_load_lds(
      (const __attribute__((address_space(1))) unsigned int*)g,
      (__attribute__((address_space(3))) unsigned int*)l, 16, 0, 0);
}

// Packed tile format (64x64 tile = 8KB): logical (r 0..63, c 0..7 16B-chunks)
// at chunk = (r>>3)*64 + (r&7)*8 + ((c^r)&7). Wpk layer layout: ushort offset
// ((nb*32 + kt)*4096) + g*512 + i*8 + j, kt 0..15 = w_ih, 16..31 = w_hh.
// Apk layer layout: mb*131072 + kt*4096 + chunk*8 (+j) -- tile-linear, so an
// A tile is one contiguous 8KB block: DMA-able AND fragment offsets in LDS
// equal the old global gather offsets.

// ---- per-layer pack (round-7 verified body, split into 4 dispatches so
// lstm_fused surfaces in the rocprof top-5). awork=640 adds the A/h0 pack
// (layer-0 dispatch only). ----
__global__ __launch_bounds__(256) void pack_init(
    const float* __restrict__ x, const float* __restrict__ h0,
    const float* __restrict__ wi, const float* __restrict__ wh,
    ushort_t* __restrict__ wdst, ushort_t* __restrict__ apk, int awork) {
  int blk = blockIdx.x;
  if (blk >= awork) {
    int u = blk - awork;                      // 0..1023
    int qb = u * 1024 + threadIdx.x;          // base chunk; j-stride 256
    u64 s0, s1, s2, s3;
    {
      u64* sp[4] = {&s0, &s1, &s2, &s3};
#pragma unroll
      for (int j = 0; j < 4; ++j) {
        int q = qb + j * 256;
        int i = q & 63, g = (q >> 6) & 7, kt = (q >> 9) & 31, nbq = q >> 14;
        int r = g * 8 + (i >> 3);
        int c = (i & 7) ^ (r & 7);
        *sp[j] = (u64)(const char*)(((kt >> 4) ? wh : wi)
            + ((size_t)((r >> 4) * 1024 + nbq * 16 + (r & 15)) << 10)
            + ((kt & 15) * 64 + c * 8));
      }
    }
    f32x4 v0a, v0b, v1a, v1b, v2a, v2b, v3a, v3b;
    GLD16(v0a, s0); GLD16(v0b, s0 + 16);
    GLD16(v1a, s1); GLD16(v1b, s1 + 16);
    GLD16(v2a, s2); GLD16(v2b, s2 + 16);
    GLD16(v3a, s3); GLD16(v3b, s3 + 16);
    WAITV0_TIE8(v0a, v0b, v1a, v1b, v2a, v2b, v3a, v3b);
#define PSTORE(J, VA, VB)                                                   \
    {                                                                       \
      short8 pk;                                                            \
      pk[0] = (short)f2bf(VA[0]); pk[1] = (short)f2bf(VA[1]);               \
      pk[2] = (short)f2bf(VA[2]); pk[3] = (short)f2bf(VA[3]);               \
      pk[4] = (short)f2bf(VB[0]); pk[5] = (short)f2bf(VB[1]);               \
      pk[6] = (short)f2bf(VB[2]); pk[7] = (short)f2bf(VB[3]);               \
      *(short8*)(wdst + (size_t)(qb + (J) * 256) * 8) = pk;                 \
    }
    PSTORE(0, v0a, v0b)
    PSTORE(1, v1a, v1b)
    PSTORE(2, v2a, v2b)
    PSTORE(3, v3a, v3b)
#undef PSTORE
    return;
  }
  int t = blk * 256 + threadIdx.x;  // 0..163839
  int lane = t & 63;
  int r8 = lane >> 3;
  int c = (lane & 7) ^ r8;
  const float* src;
  ushort_t* dst;
  if (t < 32768) {
    int g = (t >> 6) & 7, kt = (t >> 9) & 15, mb = t >> 13;
    int m = mb * 64 + g * 8 + r8;
    src = x + (size_t)m * 1024 + kt * 64 + c * 8;
    dst = apk + (size_t)mb * 131072 + (size_t)kt * 4096 + g * 512 + lane * 8;
  } else {
    int u = t - 32768;
    int g = (u >> 6) & 7, kt16 = (u >> 9) & 15, mb = (u >> 13) & 3, l = u >> 15;
    int m = mb * 64 + g * 8 + r8;
    src = h0 + (size_t)l * 262144 + (size_t)m * 1024 + kt16 * 64 + c * 8;
    dst = apk + (size_t)l * 524288 + (size_t)mb * 131072
        + (size_t)(16 + kt16) * 4096 + g * 512 + lane * 8;
  }
  float4 a = *(const float4*)src, b = *(const float4*)(src + 4);
  short8 pk;
  pk[0] = (short)f2bf(a.x); pk[1] = (short)f2bf(a.y);
  pk[2] = (short)f2bf(a.z); pk[3] = (short)f2bf(a.w);
  pk[4] = (short)f2bf(b.x); pk[5] = (short)f2bf(b.y);
  pk[6] = (short)f2bf(b.z); pk[7] = (short)f2bf(b.w);
  *(short8*)dst = pk;
}

// ---- fused layer GEMM, round-0 mechanism with A ALSO via DMA->LDS.
// Traffic model (r8/r10/r11 evidence): step time ~ per-CU VMEM-return bytes.
// Old: 8KB B DMA + 16KB A GLD16 (2x dup) = 24KB/tile. New: 8KB B + 8KB A,
// both DMA'd (wave w takes its contiguous 1KB slice of each) = 16KB/tile.
// A fragments are ds_read from LDS at the SAME chunk offsets the old global
// gather used (tile-linear apk). Loop: 2 dma16/wave/tile, quad-buffer,
// prefetch distance 3 -> 6 outstanding; PRE=4 retires tile kt's pair; the
// barrier then guarantees every wave's tile-kt DMAs landed; 6 ds_read
// (2 A + 4 B), lgkm0, 4 MFMA. No POST wait. Tail PRE: 4/2/0.
// Grid (64,4) = 1 block/CU. acc layout + epilogue byte-identical to r4. ----
__global__ __launch_bounds__(512) void lstm_fused(
    const ushort_t* __restrict__ apk, const ushort_t* __restrict__ wpk,
    const float* __restrict__ bi, const float* __restrict__ bh,
    const float* __restrict__ c0l,
    float* __restrict__ hout, float* __restrict__ cout,
    ushort_t* __restrict__ apk_next) {
  __shared__ union U {
    struct { ushort_t A[4][4096]; ushort_t B[4][4096]; } st;  // 64KB
    float sg[4 * 64 * 17];     // epilogue gate exchange (17.4KB, overlays)
  } sm;

  const int tid = threadIdx.x;
  const int nb = blockIdx.x;   // 0..63
  const int mb = blockIdx.y;   // 0..3
  const int h0c = nb * 16;
  const int m0 = mb * 64;
  const int lane = tid & 63;
  const int w = tid >> 6;
  const int wm = w & 3, wcol = w >> 2;
  const int lrow = lane & 15, lq = lane >> 4;

  // DMA sources: wave w deposits its contiguous 1KB slice of each 8KB tile
  const char* srcB = (const char*)(wpk + (size_t)nb * 131072) + w * 1024 + lane * 16;
  const char* srcA = (const char*)(apk + (size_t)mb * 131072) + w * 1024 + lane * 16;

#define CHUNK(r, c) (((r) >> 3) * 64 + ((r) & 7) * 8 + (((c) ^ (r)) & 7))
  // fragment LDS byte offsets (within a tile slot; + slot*8192)
  unsigned smb = (unsigned)(uintptr_t)(__attribute__((address_space(3))) void*)&sm;
  const int rA = wm * 16 + lrow;
  unsigned oA0 = smb + CHUNK(rA, lq) * 16;
  unsigned oA1 = smb + CHUNK(rA, 4 + lq) * 16;
  const int rB0 = wcol * 32 + lrow, rB1 = rB0 + 16;
  unsigned oB00 = smb + 32768u + CHUNK(rB0, lq) * 16;
  unsigned oB01 = smb + 32768u + CHUNK(rB0, 4 + lq) * 16;
  unsigned oB10 = smb + 32768u + CHUNK(rB1, lq) * 16;
  unsigned oB11 = smb + 32768u + CHUNK(rB1, 4 + lq) * 16;
#undef CHUNK

  f32x4 acc0 = {0.f, 0.f, 0.f, 0.f}, acc1 = {0.f, 0.f, 0.f, 0.f};

  // prologue: tiles 0,1,2 -> per tile: D_B, D_A (6 ops outstanding)
#pragma unroll
  for (int t = 0; t < 3; ++t) {
    dma16(srcB, &sm.st.B[t][w * 512]); srcB += 8192;
    dma16(srcA, &sm.st.A[t][w * 512]); srcA += 8192;
  }

#define KSTEP(S, PRE, ISSUE)                                                \
  {                                                                         \
    WAITV(PRE);                                                             \
    BAR();                                                                  \
    if (ISSUE) {                                                            \
      const int S3 = ((S) + 3) & 3;                                         \
      dma16(srcB, &sm.st.B[S3][w * 512]); srcB += 8192;                     \
      dma16(srcA, &sm.st.A[S3][w * 512]); srcA += 8192;                     \
    }                                                                       \
    short8 a0, a1, b00, b01, b10, b11;                                      \
    DSR(a0, oA0 + (S) * 8192u); DSR(a1, oA1 + (S) * 8192u);                 \
    DSR(b00, oB00 + (S) * 8192u); DSR(b10, oB10 + (S) * 8192u);             \
    DSR(b01, oB01 + (S) * 8192u); DSR(b11, oB11 + (S) * 8192u);             \
    LGKM0_TIE6(a0, a1, b00, b01, b10, b11);                                 \
    acc0 = __builtin_amdgcn_mfma_f32_16x16x32_bf16(a0, b00, acc0, 0, 0, 0); \
    acc1 = __builtin_amdgcn_mfma_f32_16x16x32_bf16(a0, b10, acc1, 0, 0, 0); \
    acc0 = __builtin_amdgcn_mfma_f32_16x16x32_bf16(a1, b01, acc0, 0, 0, 0); \
    acc1 = __builtin_amdgcn_mfma_f32_16x16x32_bf16(a1, b11, acc1, 0, 0, 0); \
  }

  // kt = 0..27 steady (7 x 4), kt=28 issues tile 31, tail retires 2/step
  for (int i = 0; i < 7; ++i) {
    KSTEP(0, 4, 1)
    KSTEP(1, 4, 1)
    KSTEP(2, 4, 1)
    KSTEP(3, 4, 1)
  }
  KSTEP(0, 4, 1)   // kt=28, issues tile 31
  KSTEP(1, 4, 0)   // kt=29: 6 outstanding -> retire tile 29 pair
  KSTEP(2, 2, 0)   // kt=30
  KSTEP(3, 0, 0)   // kt=31
#undef KSTEP

  FULLBAR();  // vmcnt already 0; drain LDS, then overlay sg over stage

  // acc layout (verified): row = m0 + wm*16 + lq*4 + r, gate = wcol*2+nt, hcol = lrow
#pragma unroll
  for (int nt = 0; nt < 2; ++nt) {
    int gate = wcol * 2 + nt;
    int rowb = wm * 16 + lq * 4;
    const f32x4& a = nt ? acc1 : acc0;
#pragma unroll
    for (int r = 0; r < 4; ++r)
      sm.sg[gate * 1088 + (rowb + r) * 17 + lrow] = a[r];
  }
  FULLBAR();

  {
    const int erow = tid >> 3, ehp = (tid & 7) * 2;
    // epilogue-only global loads: issued after all counted VM ops (safe)
    float2 cp = *(const float2*)(c0l + (size_t)(m0 + erow) * 1024 + h0c + ehp);
    float cpa[2] = {cp.x, cp.y};
    float hva[2], cva[2];
#pragma unroll
    for (int e = 0; e < 2; ++e) {
      int hc = ehp + e;
      float gi = sm.sg[0 * 1088 + erow * 17 + hc] + bi[h0c + hc]          + bh[h0c + hc];
      float gf = sm.sg[1 * 1088 + erow * 17 + hc] + bi[1024 + h0c + hc]   + bh[1024 + h0c + hc];
      float gg = sm.sg[2 * 1088 + erow * 17 + hc] + bi[2048 + h0c + hc]   + bh[2048 + h0c + hc];
      float go = sm.sg[3 * 1088 + erow * 17 + hc] + bi[3072 + h0c + hc]   + bh[3072 + h0c + hc];
      float cn = sigm(gf) * cpa[e] + sigm(gi) * tanh_(gg);
      cva[e] = cn;
      hva[e] = sigm(go) * tanh_(cn);
    }
    float2 hv; hv.x = hva[0]; hv.y = hva[1];
    float2 cv; cv.x = cva[0]; cv.y = cva[1];
    *(float2*)(hout + (size_t)(m0 + erow) * 1024 + h0c + ehp) = hv;
    *(float2*)(cout + (size_t)(m0 + erow) * 1024 + h0c + ehp) = cv;
    if (apk_next) {  // packed bf16 h for next layer's A gathers
      int g = erow >> 3;
#pragma unroll
      for (int e = 0; e < 2; ++e) {
        int k = h0c + ehp + e;
        int cc = (k >> 3) & 7, j = k & 7;
        int i = (erow & 7) * 8 + ((cc ^ erow) & 7);
        apk_next[(size_t)mb * 131072 + (size_t)(k >> 6) * 4096 + g * 512 + i * 8 + j] =
            f2bf(hva[e]);
      }
    }
  }
}

extern "C" void kernel_launch(void* const* d_in, const int* in_sizes, int n_in,
                              void* d_out, int out_size, void* d_ws, size_t ws_size,
                              hipStream_t stream) {
  const float* x    = (const float*)d_in[0];
  const float* h0   = (const float*)d_in[1];
  const float* c0   = (const float*)d_in[2];
  const float* w_ih = (const float*)d_in[3];
  const float* w_hh = (const float*)d_in[4];
  const float* b_ih = (const float*)d_in[5];
  const float* b_hh = (const float*)d_in[6];
  float* out = (float*)d_out;

  ushort_t* Wpk = (ushort_t*)d_ws;              // 4 layers x 16 MB packed bf16 W
  ushort_t* Apk = Wpk + (size_t)4 * 8388608;    // 4 layers x 1 MB packed bf16 A

  // pack, split per layer (layer 0 also packs A/h0): 4 x ~14.5us
  for (int l = 0; l < NLAYER; ++l) {
    int awork = (l == 0) ? 640 : 0;
    pack_init<<<1024 + awork, 256, 0, stream>>>(
        x, h0, w_ih + (size_t)l * 4194304, w_hh + (size_t)l * 4194304,
        Wpk + (size_t)l * 8388608, Apk, awork);
  }

  const size_t BH = (size_t)BATCH * HID;
  for (int l = 0; l < NLAYER; ++l) {
    lstm_fused<<<dim3(64, 4), 512, 0, stream>>>(
        Apk + (size_t)l * 524288, Wpk + (size_t)l * 8388608,
        b_ih + (size_t)l * 4096, b_hh + (size_t)l * 4096,
        c0 + (size_t)l * BH,
        out + (size_t)l * BH, out + (size_t)NLAYER * BH + (size_t)l * BH,
        (l < NLAYER - 1) ? Apk + (size_t)(l + 1) * 524288 : (ushort_t*)nullptr);
  }
}